// Round 1
// baseline (6597.636 us; speedup 1.0000x reference)
//
#include <hip/hip_runtime.h>
#include <hip/hip_bf16.h>
#include <math.h>

// Problem constants
#define Bv 4
#define Sv 512
#define Dv 768
#define FFv 3072
#define Vv 30000
#define Hv 12
#define Mv 64
#define DHv 64
#define NLAYERS 12

typedef __attribute__((ext_vector_type(8))) short short8;   // 8 bf16 (4 VGPRs)
typedef __attribute__((ext_vector_type(4))) float floatx4;  // MFMA accumulator

// fp32 -> bf16 (round to nearest even), returned as raw short bits
static __device__ __forceinline__ short f2b(float f) {
  union { float f; unsigned u; } v; v.f = f;
  unsigned r = v.u + 0x7fffu + ((v.u >> 16) & 1u);
  return (short)(r >> 16);
}

// ---------------- embedding: x = gather(se_w, tok) + se_b + pe ----------------
__global__ __launch_bounds__(256) void embed_kernel(
    const float* __restrict__ oh, const float* __restrict__ sew,
    const float* __restrict__ seb, float* __restrict__ xf,
    short* __restrict__ xb)
{
  int bs = blockIdx.x;            // b*S + s
  int s = bs & (Sv - 1);
  __shared__ int tokS;
  const float* row = oh + (size_t)bs * Vv;
  for (int j = threadIdx.x * 4; j < Vv; j += 256 * 4) {
    float4 f = *(const float4*)(row + j);
    if (f.x != 0.f) tokS = j;
    if (f.y != 0.f) tokS = j + 1;
    if (f.z != 0.f) tokS = j + 2;
    if (f.w != 0.f) tokS = j + 3;
  }
  __syncthreads();
  int tok = tokS;
  for (int d = threadIdx.x; d < Dv; d += 256) {
    float pe = 0.f;
    if (s > 0) {
      // denom = 10000^(2d/768); row 0 of pe stays 0 (never sin/cos'd)
      float denom = expf(9.210340371976184f * (2.f * (float)d / 768.f));
      float raw = (float)s / denom;
      pe = (d & 1) ? cosf(raw) : sinf(raw);
    }
    float val = sew[(size_t)tok * Dv + d] + seb[d] + pe;
    xf[(size_t)bs * Dv + d] = val;
    xb[(size_t)bs * Dv + d] = f2b(val);
  }
}

// ---------------- generic GEMM: C[M,N] = A[M,K](bf16) @ W[K,N](f32->bf16) + bias ----------------
// A row-major bf16 (lda=K). W row-major fp32, converted to bf16 while staged
// (transposed) into LDS. Writes fp32 (Cf) and/or bf16 (Cb). Optional ReLU.
__global__ __launch_bounds__(256) void gemm_kernel(
    const short* __restrict__ A, const float* __restrict__ W,
    const float* __restrict__ bias, float* __restrict__ Cf,
    short* __restrict__ Cb, int M, int N, int K, int relu)
{
  __shared__ __align__(16) short lw[64][40];  // lw[n][k], +8 pad keeps 16B-aligned rows
  int n0 = blockIdx.x * 64, m0 = blockIdx.y * 64;
  int tid = threadIdx.x;
  int wave = tid >> 6, lane = tid & 63, quad = lane >> 4, l16 = lane & 15;
  floatx4 acc[4];
  #pragma unroll
  for (int c = 0; c < 4; c++) acc[c] = (floatx4){0.f, 0.f, 0.f, 0.f};
  const short* Arow = A + (size_t)(m0 + wave * 16 + l16) * K;
  for (int k0 = 0; k0 < K; k0 += 32) {
    __syncthreads();
    #pragma unroll
    for (int i = 0; i < 8; i++) {           // stage W[k0:k0+32, n0:n0+64] transposed
      int idx2 = i * 256 + tid;
      int kk = idx2 >> 6, nn = idx2 & 63;
      int n = n0 + nn;
      float w = (n < N) ? W[(size_t)(k0 + kk) * N + n] : 0.f;
      lw[nn][kk] = f2b(w);
    }
    __syncthreads();
    // A-frag: lane holds A[m=l16][k=quad*8+j]
    short8 af = *(const short8*)(Arow + k0 + quad * 8);
    #pragma unroll
    for (int c = 0; c < 4; c++) {
      // B-frag: lane holds B[k=quad*8+j][n=l16]
      short8 bf = *(const short8*)(&lw[c * 16 + l16][quad * 8]);
      acc[c] = __builtin_amdgcn_mfma_f32_16x16x32_bf16(af, bf, acc[c], 0, 0, 0);
    }
  }
  // C/D: col = l16, row = quad*4 + reg
  int row = m0 + wave * 16 + quad * 4;
  #pragma unroll
  for (int c = 0; c < 4; c++) {
    int col = n0 + c * 16 + l16;
    if (col < N) {
      float bb = bias ? bias[col] : 0.f;
      #pragma unroll
      for (int r = 0; r < 4; r++) {
        float val = acc[c][r] + bb;
        if (relu) val = fmaxf(val, 0.f);
        size_t off = (size_t)(row + r) * N + col;
        if (Cf) Cf[off] = val;
        if (Cb) Cb[off] = f2b(val);
      }
    }
  }
}

// ---------------- attention scores: SC[bh,q,k] = scale * Q[b,q,h,:]·K[b,k,h,:] ----------------
__global__ __launch_bounds__(256) void scores_kernel(
    const short* __restrict__ Q, const short* __restrict__ Kb,
    float* __restrict__ SC)
{
  int n0 = blockIdx.x * 64, q0 = blockIdx.y * 64, bh = blockIdx.z;
  int b = bh / Hv, h = bh - b * Hv;
  int tid = threadIdx.x;
  int wave = tid >> 6, lane = tid & 63, quad = lane >> 4, l16 = lane & 15;
  floatx4 acc[4];
  #pragma unroll
  for (int c = 0; c < 4; c++) acc[c] = (floatx4){0.f, 0.f, 0.f, 0.f};
  const short* Qrow = Q + (size_t)(b * Sv + q0 + wave * 16 + l16) * Dv + h * DHv;
  #pragma unroll
  for (int k0 = 0; k0 < DHv; k0 += 32) {
    short8 af = *(const short8*)(Qrow + k0 + quad * 8);
    #pragma unroll
    for (int c = 0; c < 4; c++) {
      const short* Krow = Kb + (size_t)(b * Sv + n0 + c * 16 + l16) * Dv + h * DHv;
      short8 bf = *(const short8*)(Krow + k0 + quad * 8);  // B[k][n]=K[n][k]: Q@K^T
      acc[c] = __builtin_amdgcn_mfma_f32_16x16x32_bf16(af, bf, acc[c], 0, 0, 0);
    }
  }
  int row = q0 + wave * 16 + quad * 4;
  #pragma unroll
  for (int c = 0; c < 4; c++) {
    int col = n0 + c * 16 + l16;
    #pragma unroll
    for (int r = 0; r < 4; r++)
      SC[((size_t)bh * Sv + row + r) * Sv + col] = acc[c][r] * 0.125f;
  }
}

// ---------------- softmax over last dim (512), in-place fp32 ----------------
__global__ __launch_bounds__(256) void softmax_kernel(float* __restrict__ SC)
{
  float* p = SC + (size_t)blockIdx.x * Sv;
  int t = threadIdx.x;
  float a = p[t], b = p[t + 256];
  __shared__ float red[256];
  red[t] = fmaxf(a, b);
  __syncthreads();
  for (int s2 = 128; s2 > 0; s2 >>= 1) {
    if (t < s2) red[t] = fmaxf(red[t], red[t + s2]);
    __syncthreads();
  }
  float m = red[0];
  __syncthreads();
  float e1 = expf(a - m), e2 = expf(b - m);
  red[t] = e1 + e2;
  __syncthreads();
  for (int s2 = 128; s2 > 0; s2 >>= 1) {
    if (t < s2) red[t] += red[t + s2];
    __syncthreads();
  }
  float inv = 1.f / red[0];
  p[t] = e1 * inv;
  p[t + 256] = e2 * inv;
}

// ---------------- PV: O[b,q,h,:] = P[bh,q,:] @ V[b,:,h,:] ----------------
__global__ __launch_bounds__(256) void pv_kernel(
    const float* __restrict__ P, const short* __restrict__ Vb,
    short* __restrict__ O)
{
  __shared__ __align__(16) short lv[64][40];
  int q0 = blockIdx.x * 64, bh = blockIdx.y;
  int b = bh / Hv, h = bh - b * Hv;
  int tid = threadIdx.x;
  int wave = tid >> 6, lane = tid & 63, quad = lane >> 4, l16 = lane & 15;
  floatx4 acc[4];
  #pragma unroll
  for (int c = 0; c < 4; c++) acc[c] = (floatx4){0.f, 0.f, 0.f, 0.f};
  const float* Prow = P + (size_t)bh * Sv * Sv + (size_t)(q0 + wave * 16 + l16) * Sv;
  for (int k0 = 0; k0 < Sv; k0 += 32) {
    __syncthreads();
    #pragma unroll
    for (int i = 0; i < 8; i++) {          // stage V[k0:k0+32, h*64:h*64+64] transposed
      int idx2 = i * 256 + tid;
      int kk = idx2 >> 6, nn = idx2 & 63;
      lv[nn][kk] = Vb[(size_t)(b * Sv + k0 + kk) * Dv + h * DHv + nn];
    }
    __syncthreads();
    const float* pp = Prow + k0 + quad * 8;
    float4 p0 = *(const float4*)pp;
    float4 p1 = *(const float4*)(pp + 4);
    short8 af;
    af[0] = f2b(p0.x); af[1] = f2b(p0.y); af[2] = f2b(p0.z); af[3] = f2b(p0.w);
    af[4] = f2b(p1.x); af[5] = f2b(p1.y); af[6] = f2b(p1.z); af[7] = f2b(p1.w);
    #pragma unroll
    for (int c = 0; c < 4; c++) {
      short8 bf = *(const short8*)(&lv[c * 16 + l16][quad * 8]);
      acc[c] = __builtin_amdgcn_mfma_f32_16x16x32_bf16(af, bf, acc[c], 0, 0, 0);
    }
  }
  int row = q0 + wave * 16 + quad * 4;
  #pragma unroll
  for (int c = 0; c < 4; c++) {
    int col = h * DHv + c * 16 + l16;
    #pragma unroll
    for (int r = 0; r < 4; r++)
      O[(size_t)(b * Sv + row + r) * Dv + col] = f2b(acc[c][r]);
  }
}

// ---------------- residual add + layernorm: x = LN(xf + mh), dual write ----------------
__global__ __launch_bounds__(256) void addln_kernel(
    float* __restrict__ xf, const float* __restrict__ mh,
    short* __restrict__ xb)
{
  int r = blockIdx.x, t = threadIdx.x;
  size_t base = (size_t)r * Dv;
  float v[3];
  #pragma unroll
  for (int i = 0; i < 3; i++) {
    int d = t + i * 256;
    v[i] = xf[base + d] + mh[base + d];
  }
  __shared__ float red[256];
  red[t] = v[0] + v[1] + v[2];
  __syncthreads();
  for (int s2 = 128; s2 > 0; s2 >>= 1) { if (t < s2) red[t] += red[t + s2]; __syncthreads(); }
  float mean = red[0] * (1.f / 768.f);
  __syncthreads();
  float sq = 0.f;
  #pragma unroll
  for (int i = 0; i < 3; i++) { float d2 = v[i] - mean; sq += d2 * d2; }
  red[t] = sq;
  __syncthreads();
  for (int s2 = 128; s2 > 0; s2 >>= 1) { if (t < s2) red[t] += red[t + s2]; __syncthreads(); }
  float inv = rsqrtf(red[0] * (1.f / 768.f) + 1e-5f);
  #pragma unroll
  for (int i = 0; i < 3; i++) {
    int d = t + i * 256;
    float o = (v[i] - mean) * inv;
    xf[base + d] = o;
    xb[base + d] = f2b(o);
  }
}

// ---------------- gather masked rows ----------------
__global__ __launch_bounds__(256) void gather_kernel(
    const short* __restrict__ xb, const int* __restrict__ idx,
    short* __restrict__ g)
{
  int bm = blockIdx.x;            // b*M + m
  int b = bm >> 6;
  int s = idx[bm];
  for (int d = threadIdx.x; d < Dv; d += 256)
    g[(size_t)bm * Dv + d] = xb[(size_t)(b * Sv + s) * Dv + d];
}

// ---------------- log_softmax over V=30000 ----------------
__global__ __launch_bounds__(256) void lsm_kernel(
    const float* __restrict__ L, float* __restrict__ out)
{
  int r = blockIdx.x, t = threadIdx.x;
  const float* p = L + (size_t)r * Vv;
  float m = -1e30f;
  for (int j = t; j < Vv; j += 256) m = fmaxf(m, p[j]);
  __shared__ float red[256];
  red[t] = m;
  __syncthreads();
  for (int s2 = 128; s2 > 0; s2 >>= 1) { if (t < s2) red[t] = fmaxf(red[t], red[t + s2]); __syncthreads(); }
  m = red[0];
  __syncthreads();
  float s = 0.f;
  for (int j = t; j < Vv; j += 256) s += expf(p[j] - m);
  red[t] = s;
  __syncthreads();
  for (int s2 = 128; s2 > 0; s2 >>= 1) { if (t < s2) red[t] += red[t + s2]; __syncthreads(); }
  float lse = m + logf(red[0]);
  for (int j = t; j < Vv; j += 256) out[(size_t)r * Vv + j] = p[j] - lse;
}

extern "C" void kernel_launch(void* const* d_in, const int* in_sizes, int n_in,
                              void* d_out, int out_size, void* d_ws, size_t ws_size,
                              hipStream_t stream) {
  const float* oh  = (const float*)d_in[0];
  const float* sew = (const float*)d_in[1];
  const float* seb = (const float*)d_in[2];
  const float* wq  = (const float*)d_in[3];  const float* bq = (const float*)d_in[4];
  const float* wk  = (const float*)d_in[5];  const float* bk = (const float*)d_in[6];
  const float* wv  = (const float*)d_in[7];  const float* bv = (const float*)d_in[8];
  const float* wo  = (const float*)d_in[9];  const float* bo = (const float*)d_in[10];
  const float* w1  = (const float*)d_in[11]; const float* b1 = (const float*)d_in[12];
  const float* w2  = (const float*)d_in[13]; const float* b2 = (const float*)d_in[14];
  const float* we  = (const float*)d_in[15]; const float* be = (const float*)d_in[16];
  const int*   idx = (const int*)d_in[17];
  float* out = (float*)d_out;

  // workspace carve (256B aligned)
  char* p = (char*)d_ws;
  auto alloc = [&](size_t bytes) -> char* {
    char* r = p; p += (bytes + 255) & ~(size_t)255; return r;
  };
  const size_t BS = (size_t)Bv * Sv;                 // 2048
  short* xb = (short*)alloc(BS * Dv * 2);            // bf16 trunk mirror
  float* xf = (float*)alloc(BS * Dv * 4);            // fp32 trunk
  short* q  = (short*)alloc(BS * Dv * 2);
  short* k  = (short*)alloc(BS * Dv * 2);
  short* v  = (short*)alloc(BS * Dv * 2);
  short* o  = (short*)alloc(BS * Dv * 2);
  float* mh = (float*)alloc(BS * Dv * 4);            // mha out fp32
  short* t1 = (short*)alloc(BS * FFv * 2);           // ffn mid
  float* sc = (float*)alloc((size_t)Bv * Hv * Sv * Sv * 4);  // scores/probs fp32
  short* g  = (short*)alloc((size_t)Bv * Mv * Dv * 2);
  float* lg = (float*)alloc((size_t)Bv * Mv * Vv * 4);       // logits fp32

  embed_kernel<<<(int)BS, 256, 0, stream>>>(oh, sew, seb, xf, xb);

  dim3 gD(Dv / 64, (int)BS / 64);      // (12, 32) for [2048,768] outputs
  dim3 gFF(FFv / 64, (int)BS / 64);    // (48, 32) for [2048,3072]
  for (int l = 0; l < NLAYERS; l++) {
    gemm_kernel<<<gD, 256, 0, stream>>>(xb, wq, bq, nullptr, q, (int)BS, Dv, Dv, 0);
    gemm_kernel<<<gD, 256, 0, stream>>>(xb, wk, bk, nullptr, k, (int)BS, Dv, Dv, 0);
    gemm_kernel<<<gD, 256, 0, stream>>>(xb, wv, bv, nullptr, v, (int)BS, Dv, Dv, 0);
    scores_kernel<<<dim3(Sv / 64, Sv / 64, Bv * Hv), 256, 0, stream>>>(q, k, sc);
    softmax_kernel<<<Bv * Hv * Sv, 256, 0, stream>>>(sc);
    pv_kernel<<<dim3(Sv / 64, Bv * Hv), 256, 0, stream>>>(sc, v, o);
    gemm_kernel<<<gD, 256, 0, stream>>>(o, wo, bo, mh, nullptr, (int)BS, Dv, Dv, 0);
    addln_kernel<<<(int)BS, 256, 0, stream>>>(xf, mh, xb);
    gemm_kernel<<<gFF, 256, 0, stream>>>(xb, w1, b1, nullptr, t1, (int)BS, FFv, Dv, 1);
    gemm_kernel<<<gD, 256, 0, stream>>>(t1, w2, b2, xf, xb, (int)BS, Dv, FFv, 0);
  }

  gather_kernel<<<Bv * Mv, 256, 0, stream>>>(xb, idx, g);
  gemm_kernel<<<dim3((Vv + 63) / 64, (Bv * Mv) / 64), 256, 0, stream>>>(
      g, we, be, lg, nullptr, Bv * Mv, Vv, Dv, 0);
  lsm_kernel<<<Bv * Mv, 256, 0, stream>>>(lg, out);
}

// Round 2
// 2834.026 us; speedup vs baseline: 2.3280x; 2.3280x over previous
//
#include <hip/hip_runtime.h>
#include <hip/hip_bf16.h>
#include <math.h>

// Problem constants
#define Bv 4
#define Sv 512
#define Dv 768
#define FFv 3072
#define Vv 30000
#define Vpad 30080
#define Hv 12
#define Mv 64
#define DHv 64
#define NLAYERS 12
#define QKVN 2304

typedef __attribute__((ext_vector_type(8))) short short8;   // 8 bf16 (4 VGPRs)
typedef __attribute__((ext_vector_type(4))) float floatx4;  // MFMA accumulator

// fp32 -> bf16 (round to nearest even), returned as raw short bits
static __device__ __forceinline__ short f2b(float f) {
  union { float f; unsigned u; } v; v.f = f;
  unsigned r = v.u + 0x7fffu + ((v.u >> 16) & 1u);
  return (short)(r >> 16);
}

// async 16B global -> LDS (lds dest = wave-uniform base + lane*16)
#define GLD16(gp, lp) __builtin_amdgcn_global_load_lds( \
    (__attribute__((address_space(1))) void*)(gp), \
    (__attribute__((address_space(3))) void*)(lp), 16, 0, 0)

// ---------------- weight transpose+convert: W[K][N] f32 -> Wt[Nout][K] bf16 ----------------
// rows n in [N, Nout) are zero-filled (vocab padding)
__global__ __launch_bounds__(256) void transpose_w(
    const float* __restrict__ W, short* __restrict__ Wt,
    int K, int N, int Nout)
{
  __shared__ float t[32][33];
  int n0 = blockIdx.x * 32, k0 = blockIdx.y * 32;
  int tx = threadIdx.x & 31, ty = threadIdx.x >> 5;   // ty 0..7
  #pragma unroll
  for (int i = 0; i < 4; i++) {
    int k = k0 + ty + i * 8, n = n0 + tx;
    t[ty + i * 8][tx] = (n < N) ? W[(size_t)k * N + n] : 0.f;
  }
  __syncthreads();
  #pragma unroll
  for (int i = 0; i < 4; i++) {
    int n = n0 + ty + i * 8, k = k0 + tx;
    if (n < Nout) Wt[(size_t)n * K + k] = f2b(t[tx][ty + i * 8]);
  }
}

__global__ __launch_bounds__(256) void pack_bias(
    const float* __restrict__ bq, const float* __restrict__ bk,
    const float* __restrict__ bv, float* __restrict__ bqkv)
{
  int i = blockIdx.x * 256 + threadIdx.x;
  if (i < Dv) { bqkv[i] = bq[i]; bqkv[Dv + i] = bk[i]; bqkv[2 * Dv + i] = bv[i]; }
}

// ---------------- embedding: x = gather(se_w, tok) + se_b + pe ----------------
__global__ __launch_bounds__(256) void embed_kernel(
    const float* __restrict__ oh, const float* __restrict__ sew,
    const float* __restrict__ seb, float* __restrict__ xf,
    short* __restrict__ xb)
{
  int bs = blockIdx.x;            // b*S + s
  int s = bs & (Sv - 1);
  __shared__ int tokS;
  const float* row = oh + (size_t)bs * Vv;
  for (int j = threadIdx.x * 4; j < Vv; j += 256 * 4) {
    float4 f = *(const float4*)(row + j);
    if (f.x != 0.f) tokS = j;
    if (f.y != 0.f) tokS = j + 1;
    if (f.z != 0.f) tokS = j + 2;
    if (f.w != 0.f) tokS = j + 3;
  }
  __syncthreads();
  int tok = tokS;
  for (int d = threadIdx.x; d < Dv; d += 256) {
    float pe = 0.f;
    if (s > 0) {
      float denom = expf(9.210340371976184f * (2.f * (float)d / 768.f));
      float raw = (float)s / denom;
      pe = (d & 1) ? cosf(raw) : sinf(raw);
    }
    float val = sew[(size_t)tok * Dv + d] + seb[d] + pe;
    xf[(size_t)bs * Dv + d] = val;
    xb[(size_t)bs * Dv + d] = f2b(val);
  }
}

// ---------------- GEMM: C[M,N] = A[M,K]bf16 @ Bt[N,K]bf16^T + bias ----------------
// 128x128x64 tiles, global_load_lds staging with XOR-swizzled fetch mapping.
// LDS chunk (16B = 8 bf16) for (row, kc): index = row*8 + (kc ^ (row&7)).
__global__ __launch_bounds__(256) void gemm_bt(
    const short* __restrict__ A, const short* __restrict__ Bt,
    const float* __restrict__ bias, float* __restrict__ Cf,
    short* __restrict__ Cb, int M, int N, int K, int relu)
{
  __shared__ __align__(16) short As[128 * 64];
  __shared__ __align__(16) short Bs[128 * 64];
  int n0 = blockIdx.x * 128, m0 = blockIdx.y * 128;
  int tid = threadIdx.x;
  int wave = tid >> 6, lane = tid & 63, quad = lane >> 4, l16 = lane & 15;
  int wm = (wave >> 1) * 64, wn = (wave & 1) * 64;

  floatx4 acc[4][4];
  #pragma unroll
  for (int i = 0; i < 4; i++)
    #pragma unroll
    for (int j = 0; j < 4; j++) acc[i][j] = (floatx4){0.f, 0.f, 0.f, 0.f};

  // staging decode for this thread's 4 chunks (per matrix)
  int srow[4], skc[4];
  #pragma unroll
  for (int it = 0; it < 4; it++) {
    int c = it * 256 + tid;
    srow[it] = c >> 3;
    skc[it] = (c & 7) ^ (srow[it] & 7);
  }

  for (int k0 = 0; k0 < K; k0 += 64) {
    __syncthreads();
    #pragma unroll
    for (int it = 0; it < 4; it++) {
      GLD16(A + (size_t)(m0 + srow[it]) * K + k0 + skc[it] * 8,
            As + (it * 2048 + wave * 512));
      GLD16(Bt + (size_t)(n0 + srow[it]) * K + k0 + skc[it] * 8,
            Bs + (it * 2048 + wave * 512));
    }
    __syncthreads();
    #pragma unroll
    for (int kh = 0; kh < 2; kh++) {
      short8 af[4], bfr[4];
      int kc = kh * 4 + quad;
      #pragma unroll
      for (int i = 0; i < 4; i++) {
        int ra = wm + i * 16 + l16;
        af[i] = *(const short8*)(As + (ra * 8 + (kc ^ (ra & 7))) * 8);
        int rb = wn + i * 16 + l16;
        bfr[i] = *(const short8*)(Bs + (rb * 8 + (kc ^ (rb & 7))) * 8);
      }
      #pragma unroll
      for (int i = 0; i < 4; i++)
        #pragma unroll
        for (int j = 0; j < 4; j++)
          acc[i][j] = __builtin_amdgcn_mfma_f32_16x16x32_bf16(af[i], bfr[j], acc[i][j], 0, 0, 0);
    }
  }

  // C/D: col = l16, row = quad*4 + reg
  #pragma unroll
  for (int i = 0; i < 4; i++) {
    int row = m0 + wm + i * 16 + quad * 4;
    #pragma unroll
    for (int j = 0; j < 4; j++) {
      int col = n0 + wn + j * 16 + l16;
      if (col < N) {
        float bb = bias ? bias[col] : 0.f;
        #pragma unroll
        for (int r = 0; r < 4; r++) {
          float val = acc[i][j][r] + bb;
          if (relu) val = fmaxf(val, 0.f);
          size_t off = (size_t)(row + r) * N + col;
          if (Cf) Cf[off] = val;
          if (Cb) Cb[off] = f2b(val);
        }
      }
    }
  }
}

// ---------------- fused scores+softmax: probs[bh,q,:] = softmax(scale * Q K^T) ----------------
// block: 64 q-rows x 512 cols for one (b,h). Wave: 16 rows x 512 cols (acc[32]).
__global__ __launch_bounds__(256) void attn_scores(
    const short* __restrict__ qkv, short* __restrict__ probs)
{
  int q0 = blockIdx.x * 64;
  int bh = blockIdx.y;
  int b = bh / Hv, h = bh - b * Hv;
  int tid = threadIdx.x;
  int wave = tid >> 6, lane = tid & 63, quad = lane >> 4, l16 = lane & 15;
  floatx4 acc[32];
  #pragma unroll
  for (int c = 0; c < 32; c++) acc[c] = (floatx4){0.f, 0.f, 0.f, 0.f};

  const short* Qrow = qkv + (size_t)(b * Sv + q0 + wave * 16 + l16) * QKVN + h * DHv;
  short8 a0 = *(const short8*)(Qrow + quad * 8);
  short8 a1 = *(const short8*)(Qrow + 32 + quad * 8);
  const short* Kbase = qkv + Dv + (size_t)(b * Sv + l16) * QKVN + h * DHv + quad * 8;
  #pragma unroll
  for (int c = 0; c < 32; c++) {
    const short* Kp = Kbase + (size_t)c * 16 * QKVN;
    short8 b0 = *(const short8*)(Kp);
    short8 b1 = *(const short8*)(Kp + 32);
    acc[c] = __builtin_amdgcn_mfma_f32_16x16x32_bf16(a0, b0, acc[c], 0, 0, 0);
    acc[c] = __builtin_amdgcn_mfma_f32_16x16x32_bf16(a1, b1, acc[c], 0, 0, 0);
  }

  float inv[4];
  #pragma unroll
  for (int r = 0; r < 4; r++) {
    float m = -1e30f;
    #pragma unroll
    for (int c = 0; c < 32; c++) m = fmaxf(m, acc[c][r]);
    m = fmaxf(m, __shfl_xor(m, 1));
    m = fmaxf(m, __shfl_xor(m, 2));
    m = fmaxf(m, __shfl_xor(m, 4));
    m = fmaxf(m, __shfl_xor(m, 8));
    float s = 0.f;
    #pragma unroll
    for (int c = 0; c < 32; c++) {
      float e = __expf((acc[c][r] - m) * 0.125f);
      acc[c][r] = e; s += e;
    }
    s += __shfl_xor(s, 1);
    s += __shfl_xor(s, 2);
    s += __shfl_xor(s, 4);
    s += __shfl_xor(s, 8);
    inv[r] = 1.f / s;
  }

  int rowbase = q0 + wave * 16 + quad * 4;
  #pragma unroll
  for (int c = 0; c < 32; c++) {
    int col = c * 16 + l16;
    #pragma unroll
    for (int r = 0; r < 4; r++)
      probs[((size_t)bh * Sv + rowbase + r) * Sv + col] = f2b(acc[c][r] * inv[r]);
  }
}

// ---------------- PV: O[b,q,h,:] = P[bh,q,:] @ V[b,:,h,:] ----------------
__global__ __launch_bounds__(256) void pv_kernel(
    const short* __restrict__ P, const short* __restrict__ qkv,
    short* __restrict__ O)
{
  __shared__ __align__(16) short lv[64][40];
  int q0 = blockIdx.x * 64, bh = blockIdx.y;
  int b = bh / Hv, h = bh - b * Hv;
  int tid = threadIdx.x;
  int wave = tid >> 6, lane = tid & 63, quad = lane >> 4, l16 = lane & 15;
  floatx4 acc[4];
  #pragma unroll
  for (int c = 0; c < 4; c++) acc[c] = (floatx4){0.f, 0.f, 0.f, 0.f};
  const short* Prow = P + (size_t)bh * Sv * Sv + (size_t)(q0 + wave * 16 + l16) * Sv;
  for (int k0 = 0; k0 < Sv; k0 += 32) {
    __syncthreads();
    #pragma unroll
    for (int i = 0; i < 8; i++) {          // stage V[k0:k0+32, h*64:h*64+64] transposed
      int idx2 = i * 256 + tid;
      int kk = idx2 >> 6, nn = idx2 & 63;
      lv[nn][kk] = qkv[(size_t)(b * Sv + k0 + kk) * QKVN + 2 * Dv + h * DHv + nn];
    }
    __syncthreads();
    short8 af = *(const short8*)(Prow + k0 + quad * 8);
    #pragma unroll
    for (int c = 0; c < 4; c++) {
      short8 bf = *(const short8*)(&lv[c * 16 + l16][quad * 8]);
      acc[c] = __builtin_amdgcn_mfma_f32_16x16x32_bf16(af, bf, acc[c], 0, 0, 0);
    }
  }
  int row = q0 + wave * 16 + quad * 4;
  #pragma unroll
  for (int c = 0; c < 4; c++) {
    int col = h * DHv + c * 16 + l16;
    #pragma unroll
    for (int r = 0; r < 4; r++)
      O[(size_t)(b * Sv + row + r) * Dv + col] = f2b(acc[c][r]);
  }
}

// ---------------- residual add + layernorm: x = LN(xf + mh), dual write ----------------
__global__ __launch_bounds__(256) void addln_kernel(
    float* __restrict__ xf, const float* __restrict__ mh,
    short* __restrict__ xb)
{
  int r = blockIdx.x, t = threadIdx.x;
  size_t base = (size_t)r * Dv;
  float v[3];
  #pragma unroll
  for (int i = 0; i < 3; i++) {
    int d = t + i * 256;
    v[i] = xf[base + d] + mh[base + d];
  }
  __shared__ float red[256];
  red[t] = v[0] + v[1] + v[2];
  __syncthreads();
  for (int s2 = 128; s2 > 0; s2 >>= 1) { if (t < s2) red[t] += red[t + s2]; __syncthreads(); }
  float mean = red[0] * (1.f / 768.f);
  __syncthreads();
  float sq = 0.f;
  #pragma unroll
  for (int i = 0; i < 3; i++) { float d2 = v[i] - mean; sq += d2 * d2; }
  red[t] = sq;
  __syncthreads();
  for (int s2 = 128; s2 > 0; s2 >>= 1) { if (t < s2) red[t] += red[t + s2]; __syncthreads(); }
  float inv = rsqrtf(red[0] * (1.f / 768.f) + 1e-5f);
  #pragma unroll
  for (int i = 0; i < 3; i++) {
    int d = t + i * 256;
    float o = (v[i] - mean) * inv;
    xf[base + d] = o;
    xb[base + d] = f2b(o);
  }
}

// ---------------- gather masked rows ----------------
__global__ __launch_bounds__(256) void gather_kernel(
    const short* __restrict__ xb, const int* __restrict__ idx,
    short* __restrict__ g)
{
  int bm = blockIdx.x;            // b*M + m
  int b = bm >> 6;
  int s = idx[bm];
  for (int d = threadIdx.x; d < Dv; d += 256)
    g[(size_t)bm * Dv + d] = xb[(size_t)(b * Sv + s) * Dv + d];
}

// ---------------- log_softmax over V=30000 ----------------
__global__ __launch_bounds__(256) void lsm_kernel(
    const float* __restrict__ L, float* __restrict__ out)
{
  int r = blockIdx.x, t = threadIdx.x;
  const float* p = L + (size_t)r * Vv;
  float m = -1e30f;
  for (int j = t; j < Vv; j += 256) m = fmaxf(m, p[j]);
  __shared__ float red[256];
  red[t] = m;
  __syncthreads();
  for (int s2 = 128; s2 > 0; s2 >>= 1) { if (t < s2) red[t] = fmaxf(red[t], red[t + s2]); __syncthreads(); }
  m = red[0];
  __syncthreads();
  float s = 0.f;
  for (int j = t; j < Vv; j += 256) s += expf(p[j] - m);
  red[t] = s;
  __syncthreads();
  for (int s2 = 128; s2 > 0; s2 >>= 1) { if (t < s2) red[t] += red[t + s2]; __syncthreads(); }
  float lse = m + logf(red[0]);
  for (int j = t; j < Vv; j += 256) out[(size_t)r * Vv + j] = p[j] - lse;
}

extern "C" void kernel_launch(void* const* d_in, const int* in_sizes, int n_in,
                              void* d_out, int out_size, void* d_ws, size_t ws_size,
                              hipStream_t stream) {
  const float* oh  = (const float*)d_in[0];
  const float* sew = (const float*)d_in[1];
  const float* seb = (const float*)d_in[2];
  const float* wq  = (const float*)d_in[3];  const float* bq = (const float*)d_in[4];
  const float* wk  = (const float*)d_in[5];  const float* bk = (const float*)d_in[6];
  const float* wv  = (const float*)d_in[7];  const float* bv = (const float*)d_in[8];
  const float* wo  = (const float*)d_in[9];  const float* bo = (const float*)d_in[10];
  const float* w1  = (const float*)d_in[11]; const float* b1 = (const float*)d_in[12];
  const float* w2  = (const float*)d_in[13]; const float* b2 = (const float*)d_in[14];
  const float* we  = (const float*)d_in[15]; const float* be = (const float*)d_in[16];
  const int*   idx = (const int*)d_in[17];
  float* out = (float*)d_out;

  // workspace carve (256B aligned)
  char* p = (char*)d_ws;
  auto alloc = [&](size_t bytes) -> char* {
    char* r = p; p += (bytes + 255) & ~(size_t)255; return r;
  };
  const size_t BS = (size_t)Bv * Sv;                       // 2048
  short* wqkv_t = (short*)alloc((size_t)QKVN * Dv * 2);    // [2304][768] bf16
  short* wo_t   = (short*)alloc((size_t)Dv * Dv * 2);      // [768][768]
  short* w1_t   = (short*)alloc((size_t)FFv * Dv * 2);     // [3072][768]
  short* w2_t   = (short*)alloc((size_t)Dv * FFv * 2);     // [768][3072]
  float* bqkv   = (float*)alloc(QKVN * 4);
  short* xb     = (short*)alloc(BS * Dv * 2);              // bf16 trunk mirror
  float* xf     = (float*)alloc(BS * Dv * 4);              // fp32 trunk
  short* g      = (short*)alloc((size_t)Bv * Mv * Dv * 2);
  char*  TR     = p;                                        // transient union
  // layer-phase views
  short* qkv   = (short*)TR;                                          // [2048][2304] bf16
  short* o     = (short*)(TR + ((BS * QKVN * 2 + 255) & ~(size_t)255));
  float* mh    = (float*)((char*)o + ((BS * Dv * 2 + 255) & ~(size_t)255));
  short* t1    = (short*)((char*)mh + ((BS * Dv * 4 + 255) & ~(size_t)255));
  short* probs = (short*)((char*)t1 + ((BS * FFv * 2 + 255) & ~(size_t)255));
  // final-phase views (alias layer phase; used only after the loop)
  short* we_t = (short*)TR;                                           // [30080][768] bf16
  float* lg   = (float*)(TR + (((size_t)Vpad * Dv * 2 + 255) & ~(size_t)255));

  // ---- one-time weight preprocessing (bf16, transposed) ----
  transpose_w<<<dim3(24, 24), 256, 0, stream>>>(wq, wqkv_t,            Dv, Dv, Dv);
  transpose_w<<<dim3(24, 24), 256, 0, stream>>>(wk, wqkv_t + Dv * Dv,  Dv, Dv, Dv);
  transpose_w<<<dim3(24, 24), 256, 0, stream>>>(wv, wqkv_t + 2*Dv*Dv,  Dv, Dv, Dv);
  transpose_w<<<dim3(24, 24), 256, 0, stream>>>(wo, wo_t,              Dv, Dv, Dv);
  transpose_w<<<dim3(96, 24), 256, 0, stream>>>(w1, w1_t,              Dv, FFv, FFv);
  transpose_w<<<dim3(24, 96), 256, 0, stream>>>(w2, w2_t,              FFv, Dv, Dv);
  pack_bias<<<3, 256, 0, stream>>>(bq, bk, bv, bqkv);

  embed_kernel<<<(int)BS, 256, 0, stream>>>(oh, sew, seb, xf, xb);

  dim3 gQKV(QKVN / 128, (int)BS / 128);   // (18, 16)
  dim3 gD(Dv / 128, (int)BS / 128);       // (6, 16)
  dim3 gFF(FFv / 128, (int)BS / 128);     // (24, 16)
  for (int l = 0; l < NLAYERS; l++) {
    gemm_bt<<<gQKV, 256, 0, stream>>>(xb, wqkv_t, bqkv, nullptr, qkv, (int)BS, QKVN, Dv, 0);
    attn_scores<<<dim3(Sv / 64, Bv * Hv), 256, 0, stream>>>(qkv, probs);
    pv_kernel<<<dim3(Sv / 64, Bv * Hv), 256, 0, stream>>>(probs, qkv, o);
    gemm_bt<<<gD, 256, 0, stream>>>(o, wo_t, bo, mh, nullptr, (int)BS, Dv, Dv, 0);
    addln_kernel<<<(int)BS, 256, 0, stream>>>(xf, mh, xb);
    gemm_bt<<<gFF, 256, 0, stream>>>(xb, w1_t, b1, nullptr, t1, (int)BS, FFv, Dv, 1);
    gemm_bt<<<gD, 256, 0, stream>>>(t1, w2_t, b2, xf, xb, (int)BS, Dv, FFv, 0);
  }

  // vocab projection (we_t aliases the dead layer buffers)
  transpose_w<<<dim3(940, 24), 256, 0, stream>>>(we, we_t, Dv, Vv, Vpad);
  gather_kernel<<<Bv * Mv, 256, 0, stream>>>(xb, idx, g);
  gemm_bt<<<dim3(Vpad / 128, (Bv * Mv) / 128), 256, 0, stream>>>(
      g, we_t, be, lg, nullptr, Bv * Mv, Vv, Dv, 0);
  lsm_kernel<<<Bv * Mv, 256, 0, stream>>>(lg, out);
}

// Round 3
// 2423.520 us; speedup vs baseline: 2.7223x; 1.1694x over previous
//
#include <hip/hip_runtime.h>
#include <hip/hip_bf16.h>
#include <math.h>

// Problem constants
#define Bv 4
#define Sv 512
#define Dv 768
#define FFv 3072
#define Vv 30000
#define Vpad 30080
#define Hv 12
#define Mv 64
#define DHv 64
#define NLAYERS 12
#define QKVN 2304

typedef __attribute__((ext_vector_type(8))) short short8;   // 8 bf16 (4 VGPRs)
typedef __attribute__((ext_vector_type(4))) float floatx4;  // MFMA accumulator

// fp32 -> bf16 (round to nearest even), returned as raw short bits
static __device__ __forceinline__ short f2b(float f) {
  union { float f; unsigned u; } v; v.f = f;
  unsigned r = v.u + 0x7fffu + ((v.u >> 16) & 1u);
  return (short)(r >> 16);
}

// async 16B global -> LDS (lds dest = wave-uniform base + lane*16)
#define GLD16(gp, lp) __builtin_amdgcn_global_load_lds( \
    (__attribute__((address_space(1))) void*)(gp), \
    (__attribute__((address_space(3))) void*)(lp), 16, 0, 0)

// ---------------- weight transpose+convert: W[K][N] f32 -> Wt[Nout][K] bf16 ----------------
__global__ __launch_bounds__(256) void transpose_w(
    const float* __restrict__ W, short* __restrict__ Wt,
    int K, int N, int Nout)
{
  __shared__ float t[32][33];
  int n0 = blockIdx.x * 32, k0 = blockIdx.y * 32;
  int tx = threadIdx.x & 31, ty = threadIdx.x >> 5;   // ty 0..7
  #pragma unroll
  for (int i = 0; i < 4; i++) {
    int k = k0 + ty + i * 8, n = n0 + tx;
    t[ty + i * 8][tx] = (n < N) ? W[(size_t)k * N + n] : 0.f;
  }
  __syncthreads();
  #pragma unroll
  for (int i = 0; i < 4; i++) {
    int n = n0 + ty + i * 8, k = k0 + tx;
    if (n < Nout) Wt[(size_t)n * K + k] = f2b(t[tx][ty + i * 8]);
  }
}

__global__ __launch_bounds__(256) void pack_bias(
    const float* __restrict__ bq, const float* __restrict__ bk,
    const float* __restrict__ bv, float* __restrict__ bqkv)
{
  int i = blockIdx.x * 256 + threadIdx.x;
  if (i < Dv) { bqkv[i] = bq[i]; bqkv[Dv + i] = bk[i]; bqkv[2 * Dv + i] = bv[i]; }
}

// ---------------- embedding: x = gather(se_w, tok) + se_b + pe ----------------
__global__ __launch_bounds__(256) void embed_kernel(
    const float* __restrict__ oh, const float* __restrict__ sew,
    const float* __restrict__ seb, float* __restrict__ xf,
    short* __restrict__ xb)
{
  int bs = blockIdx.x;            // b*S + s
  int s = bs & (Sv - 1);
  __shared__ int tokS;
  const float* row = oh + (size_t)bs * Vv;
  for (int j = threadIdx.x * 4; j < Vv; j += 256 * 4) {
    float4 f = *(const float4*)(row + j);
    if (f.x != 0.f) tokS = j;
    if (f.y != 0.f) tokS = j + 1;
    if (f.z != 0.f) tokS = j + 2;
    if (f.w != 0.f) tokS = j + 3;
  }
  __syncthreads();
  int tok = tokS;
  for (int d = threadIdx.x; d < Dv; d += 256) {
    float pe = 0.f;
    if (s > 0) {
      float denom = expf(9.210340371976184f * (2.f * (float)d / 768.f));
      float raw = (float)s / denom;
      pe = (d & 1) ? cosf(raw) : sinf(raw);
    }
    float val = sew[(size_t)tok * Dv + d] + seb[d] + pe;
    xf[(size_t)bs * Dv + d] = val;
    xb[(size_t)bs * Dv + d] = f2b(val);
  }
}

// ---------------- GEMM: C[M,N] = A[M,K]bf16 @ Bt[N,K]bf16^T + bias ----------------
// BMxBNx64 tiles, 4 waves in 2x2 (WM x WN each), global_load_lds staging with
// XOR-swizzled fetch mapping: chunk(row,kc) at LDS index row*8 + (kc^(row&7)).
template <int BM, int BN, int WM, int WN>
__global__ __launch_bounds__(256) void gemm_bt(
    const short* __restrict__ A, const short* __restrict__ Bt,
    const float* __restrict__ bias, float* __restrict__ Cf,
    short* __restrict__ Cb, int M, int N, int K, int relu)
{
  __shared__ __align__(16) short As[BM * 64];
  __shared__ __align__(16) short Bs[BN * 64];
  int n0 = blockIdx.x * BN, m0 = blockIdx.y * BM;
  int tid = threadIdx.x;
  int wave = tid >> 6, lane = tid & 63, quad = lane >> 4, l16 = lane & 15;
  int wm = (wave >> 1) * WM, wn = (wave & 1) * WN;

  floatx4 acc[WM / 16][WN / 16];
  #pragma unroll
  for (int i = 0; i < WM / 16; i++)
    #pragma unroll
    for (int j = 0; j < WN / 16; j++) acc[i][j] = (floatx4){0.f, 0.f, 0.f, 0.f};

  // staging decode (chunk linear index = it*256 + tid)
  int srow[4], skc[4];
  #pragma unroll
  for (int it = 0; it < 4; it++) {
    int c = it * 256 + tid;
    srow[it] = c >> 3;
    skc[it] = (c & 7) ^ (srow[it] & 7);
  }

  for (int k0 = 0; k0 < K; k0 += 64) {
    __syncthreads();
    #pragma unroll
    for (int it = 0; it < BM / 32; it++)
      GLD16(A + (size_t)(m0 + srow[it]) * K + k0 + skc[it] * 8,
            As + (it * 2048 + wave * 512));
    #pragma unroll
    for (int it = 0; it < BN / 32; it++)
      GLD16(Bt + (size_t)(n0 + srow[it]) * K + k0 + skc[it] * 8,
            Bs + (it * 2048 + wave * 512));
    __syncthreads();
    #pragma unroll
    for (int kh = 0; kh < 2; kh++) {
      short8 af[WM / 16], bfr[WN / 16];
      int kc = kh * 4 + quad;
      #pragma unroll
      for (int i = 0; i < WM / 16; i++) {
        int ra = wm + i * 16 + l16;
        af[i] = *(const short8*)(As + (ra * 8 + (kc ^ (ra & 7))) * 8);
      }
      #pragma unroll
      for (int j = 0; j < WN / 16; j++) {
        int rb = wn + j * 16 + l16;
        bfr[j] = *(const short8*)(Bs + (rb * 8 + (kc ^ (rb & 7))) * 8);
      }
      #pragma unroll
      for (int i = 0; i < WM / 16; i++)
        #pragma unroll
        for (int j = 0; j < WN / 16; j++)
          acc[i][j] = __builtin_amdgcn_mfma_f32_16x16x32_bf16(af[i], bfr[j], acc[i][j], 0, 0, 0);
    }
  }

  // C/D: col = l16, row = quad*4 + reg
  #pragma unroll
  for (int i = 0; i < WM / 16; i++) {
    int row = m0 + wm + i * 16 + quad * 4;
    #pragma unroll
    for (int j = 0; j < WN / 16; j++) {
      int col = n0 + wn + j * 16 + l16;
      if (col < N) {
        float bb = bias ? bias[col] : 0.f;
        #pragma unroll
        for (int r = 0; r < 4; r++) {
          float val = acc[i][j][r] + bb;
          if (relu) val = fmaxf(val, 0.f);
          size_t off = (size_t)(row + r) * N + col;
          if (Cf) Cf[off] = val;
          if (Cb) Cb[off] = f2b(val);
        }
      }
    }
  }
}

// ---------------- fused attention: O = softmax(scale*Q K^T) V, one (b,h,q-tile) per block --------
// Phase 1: per-wave 16x512 scores in regs + online softmax (as before).
// Phase 2: per 32-col chunk: P(regs,C-layout) -> LDS -> A-frag; V^T staged in
// shared LDS once per chunk (all 4 waves reuse); 4 MFMAs -> O accum.
__global__ __launch_bounds__(256) void attn_fused(
    const short* __restrict__ qkv, short* __restrict__ O)
{
  __shared__ __align__(16) short lv[64][40];       // V^T chunk: lv[n][k]
  __shared__ __align__(16) short pbuf[4][16][40];  // per-wave P chunk, A-layout
  int q0 = blockIdx.x * 64;
  int bh = blockIdx.y;
  int b = bh / Hv, h = bh - b * Hv;
  int tid = threadIdx.x;
  int wave = tid >> 6, lane = tid & 63, quad = lane >> 4, l16 = lane & 15;

  floatx4 acc[32];
  #pragma unroll
  for (int c = 0; c < 32; c++) acc[c] = (floatx4){0.f, 0.f, 0.f, 0.f};

  const short* Qrow = qkv + (size_t)(b * Sv + q0 + wave * 16 + l16) * QKVN + h * DHv;
  short8 a0 = *(const short8*)(Qrow + quad * 8);
  short8 a1 = *(const short8*)(Qrow + 32 + quad * 8);
  const short* Kbase = qkv + Dv + (size_t)(b * Sv + l16) * QKVN + h * DHv + quad * 8;
  #pragma unroll
  for (int c = 0; c < 32; c++) {
    const short* Kp = Kbase + (size_t)c * 16 * QKVN;
    short8 b0 = *(const short8*)(Kp);
    short8 b1 = *(const short8*)(Kp + 32);
    acc[c] = __builtin_amdgcn_mfma_f32_16x16x32_bf16(a0, b0, acc[c], 0, 0, 0);
    acc[c] = __builtin_amdgcn_mfma_f32_16x16x32_bf16(a1, b1, acc[c], 0, 0, 0);
  }

  float inv[4];
  #pragma unroll
  for (int r = 0; r < 4; r++) {
    float m = -1e30f;
    #pragma unroll
    for (int c = 0; c < 32; c++) m = fmaxf(m, acc[c][r]);
    m = fmaxf(m, __shfl_xor(m, 1));
    m = fmaxf(m, __shfl_xor(m, 2));
    m = fmaxf(m, __shfl_xor(m, 4));
    m = fmaxf(m, __shfl_xor(m, 8));
    float s = 0.f;
    #pragma unroll
    for (int c = 0; c < 32; c++) {
      float e = __expf((acc[c][r] - m) * 0.125f);
      acc[c][r] = e; s += e;
    }
    s += __shfl_xor(s, 1);
    s += __shfl_xor(s, 2);
    s += __shfl_xor(s, 4);
    s += __shfl_xor(s, 8);
    inv[r] = 1.f / s;
  }

  // Phase 2: O[16x64 per wave] = P @ V
  floatx4 acc_o[4];
  #pragma unroll
  for (int j = 0; j < 4; j++) acc_o[j] = (floatx4){0.f, 0.f, 0.f, 0.f};

  const short* Vbase = qkv + 2 * Dv + h * DHv + (size_t)(b * Sv) * QKVN;
  for (int kc = 0; kc < 16; kc++) {      // k0 = kc*32
    __syncthreads();                     // lv reuse guard
    // stage V[k0..k0+32][0..64] transposed; short2 reads, 4 per thread
    #pragma unroll
    for (int i = 0; i < 4; i++) {
      int u = i * 256 + tid;
      int kk = u >> 5, nn2 = (u & 31) * 2;
      const short* vp = Vbase + (size_t)(kc * 32 + kk) * QKVN + nn2;
      short v0 = vp[0], v1 = vp[1];
      lv[nn2][kk] = v0;
      lv[nn2 + 1][kk] = v1;
    }
    // write this wave's P chunk (cols kc*32..+32) into pbuf in [m][k] layout
    #pragma unroll
    for (int half = 0; half < 2; half++) {
      int c = 2 * kc + half;
      #pragma unroll
      for (int r = 0; r < 4; r++)
        pbuf[wave][quad * 4 + r][half * 16 + l16] = f2b(acc[c][r] * inv[r]);
    }
    __syncthreads();
    short8 af = *(const short8*)(&pbuf[wave][l16][quad * 8]);
    #pragma unroll
    for (int j = 0; j < 4; j++) {
      short8 bf = *(const short8*)(&lv[j * 16 + l16][quad * 8]);
      acc_o[j] = __builtin_amdgcn_mfma_f32_16x16x32_bf16(af, bf, acc_o[j], 0, 0, 0);
    }
  }

  int row = q0 + wave * 16 + quad * 4;
  #pragma unroll
  for (int j = 0; j < 4; j++) {
    int col = h * DHv + j * 16 + l16;
    #pragma unroll
    for (int r = 0; r < 4; r++)
      O[(size_t)(b * Sv + row + r) * Dv + col] = f2b(acc_o[j][r]);
  }
}

// ---------------- residual add + layernorm: x = LN(xf + mh), dual write ----------------
__global__ __launch_bounds__(256) void addln_kernel(
    float* __restrict__ xf, const float* __restrict__ mh,
    short* __restrict__ xb)
{
  int r = blockIdx.x, t = threadIdx.x;
  size_t base = (size_t)r * Dv;
  float v[3];
  #pragma unroll
  for (int i = 0; i < 3; i++) {
    int d = t + i * 256;
    v[i] = xf[base + d] + mh[base + d];
  }
  __shared__ float red[256];
  red[t] = v[0] + v[1] + v[2];
  __syncthreads();
  for (int s2 = 128; s2 > 0; s2 >>= 1) { if (t < s2) red[t] += red[t + s2]; __syncthreads(); }
  float mean = red[0] * (1.f / 768.f);
  __syncthreads();
  float sq = 0.f;
  #pragma unroll
  for (int i = 0; i < 3; i++) { float d2 = v[i] - mean; sq += d2 * d2; }
  red[t] = sq;
  __syncthreads();
  for (int s2 = 128; s2 > 0; s2 >>= 1) { if (t < s2) red[t] += red[t + s2]; __syncthreads(); }
  float inv = rsqrtf(red[0] * (1.f / 768.f) + 1e-5f);
  #pragma unroll
  for (int i = 0; i < 3; i++) {
    int d = t + i * 256;
    float o = (v[i] - mean) * inv;
    xf[base + d] = o;
    xb[base + d] = f2b(o);
  }
}

// ---------------- gather masked rows ----------------
__global__ __launch_bounds__(256) void gather_kernel(
    const short* __restrict__ xb, const int* __restrict__ idx,
    short* __restrict__ g)
{
  int bm = blockIdx.x;            // b*M + m
  int b = bm >> 6;
  int s = idx[bm];
  for (int d = threadIdx.x; d < Dv; d += 256)
    g[(size_t)bm * Dv + d] = xb[(size_t)(b * Sv + s) * Dv + d];
}

// ---------------- log_softmax over V=30000 ----------------
__global__ __launch_bounds__(256) void lsm_kernel(
    const float* __restrict__ L, float* __restrict__ out)
{
  int r = blockIdx.x, t = threadIdx.x;
  const float* p = L + (size_t)r * Vv;
  float m = -1e30f;
  for (int j = t; j < Vv; j += 256) m = fmaxf(m, p[j]);
  __shared__ float red[256];
  red[t] = m;
  __syncthreads();
  for (int s2 = 128; s2 > 0; s2 >>= 1) { if (t < s2) red[t] = fmaxf(red[t], red[t + s2]); __syncthreads(); }
  m = red[0];
  __syncthreads();
  float s = 0.f;
  for (int j = t; j < Vv; j += 256) s += expf(p[j] - m);
  red[t] = s;
  __syncthreads();
  for (int s2 = 128; s2 > 0; s2 >>= 1) { if (t < s2) red[t] += red[t + s2]; __syncthreads(); }
  float lse = m + logf(red[0]);
  for (int j = t; j < Vv; j += 256) out[(size_t)r * Vv + j] = p[j] - lse;
}

extern "C" void kernel_launch(void* const* d_in, const int* in_sizes, int n_in,
                              void* d_out, int out_size, void* d_ws, size_t ws_size,
                              hipStream_t stream) {
  const float* oh  = (const float*)d_in[0];
  const float* sew = (const float*)d_in[1];
  const float* seb = (const float*)d_in[2];
  const float* wq  = (const float*)d_in[3];  const float* bq = (const float*)d_in[4];
  const float* wk  = (const float*)d_in[5];  const float* bk = (const float*)d_in[6];
  const float* wv  = (const float*)d_in[7];  const float* bv = (const float*)d_in[8];
  const float* wo  = (const float*)d_in[9];  const float* bo = (const float*)d_in[10];
  const float* w1  = (const float*)d_in[11]; const float* b1 = (const float*)d_in[12];
  const float* w2  = (const float*)d_in[13]; const float* b2 = (const float*)d_in[14];
  const float* we  = (const float*)d_in[15]; const float* be = (const float*)d_in[16];
  const int*   idx = (const int*)d_in[17];
  float* out = (float*)d_out;

  // workspace carve (256B aligned)
  char* p = (char*)d_ws;
  auto alloc = [&](size_t bytes) -> char* {
    char* r = p; p += (bytes + 255) & ~(size_t)255; return r;
  };
  const size_t BS = (size_t)Bv * Sv;                       // 2048
  short* wqkv_t = (short*)alloc((size_t)QKVN * Dv * 2);    // [2304][768] bf16
  short* wo_t   = (short*)alloc((size_t)Dv * Dv * 2);      // [768][768]
  short* w1_t   = (short*)alloc((size_t)FFv * Dv * 2);     // [3072][768]
  short* w2_t   = (short*)alloc((size_t)Dv * FFv * 2);     // [768][3072]
  float* bqkv   = (float*)alloc(QKVN * 4);
  short* xb     = (short*)alloc(BS * Dv * 2);              // bf16 trunk mirror
  float* xf     = (float*)alloc(BS * Dv * 4);              // fp32 trunk
  short* g      = (short*)alloc((size_t)Bv * Mv * Dv * 2);
  char*  TR     = p;                                        // transient union
  // layer-phase views
  short* qkv   = (short*)TR;                                          // [2048][2304] bf16
  short* o     = (short*)(TR + ((BS * QKVN * 2 + 255) & ~(size_t)255));
  float* mh    = (float*)((char*)o + ((BS * Dv * 2 + 255) & ~(size_t)255));
  short* t1    = (short*)((char*)mh + ((BS * Dv * 4 + 255) & ~(size_t)255));
  // final-phase views (alias layer phase; used only after the loop)
  short* we_t = (short*)TR;                                           // [30080][768] bf16
  float* lg   = (float*)(TR + (((size_t)Vpad * Dv * 2 + 255) & ~(size_t)255));

  // ---- one-time weight preprocessing (bf16, transposed) ----
  transpose_w<<<dim3(24, 24), 256, 0, stream>>>(wq, wqkv_t,            Dv, Dv, Dv);
  transpose_w<<<dim3(24, 24), 256, 0, stream>>>(wk, wqkv_t + Dv * Dv,  Dv, Dv, Dv);
  transpose_w<<<dim3(24, 24), 256, 0, stream>>>(wv, wqkv_t + 2*Dv*Dv,  Dv, Dv, Dv);
  transpose_w<<<dim3(24, 24), 256, 0, stream>>>(wo, wo_t,              Dv, Dv, Dv);
  transpose_w<<<dim3(96, 24), 256, 0, stream>>>(w1, w1_t,              Dv, FFv, FFv);
  transpose_w<<<dim3(24, 96), 256, 0, stream>>>(w2, w2_t,              FFv, Dv, Dv);
  pack_bias<<<3, 256, 0, stream>>>(bq, bk, bv, bqkv);

  embed_kernel<<<(int)BS, 256, 0, stream>>>(oh, sew, seb, xf, xb);

  dim3 gQKV(QKVN / 128, (int)BS / 128);   // (18, 16) = 288 blocks
  dim3 gD64(Dv / 64, (int)BS / 64);       // (12, 32) = 384 blocks (N=768 GEMMs)
  dim3 gFF(FFv / 128, (int)BS / 128);     // (24, 16) = 384 blocks
  for (int l = 0; l < NLAYERS; l++) {
    gemm_bt<128,128,64,64><<<gQKV, 256, 0, stream>>>(xb, wqkv_t, bqkv, nullptr, qkv, (int)BS, QKVN, Dv, 0);
    attn_fused<<<dim3(Sv / 64, Bv * Hv), 256, 0, stream>>>(qkv, o);
    gemm_bt<64,64,32,32><<<gD64, 256, 0, stream>>>(o, wo_t, bo, mh, nullptr, (int)BS, Dv, Dv, 0);
    addln_kernel<<<(int)BS, 256, 0, stream>>>(xf, mh, xb);
    gemm_bt<128,128,64,64><<<gFF, 256, 0, stream>>>(xb, w1_t, b1, nullptr, t1, (int)BS, FFv, Dv, 1);
    gemm_bt<64,64,32,32><<<gD64, 256, 0, stream>>>(t1, w2_t, b2, xf, xb, (int)BS, Dv, FFv, 0);
  }

  // vocab projection (we_t aliases the dead layer buffers)
  transpose_w<<<dim3(940, 24), 256, 0, stream>>>(we, we_t, Dv, Vv, Vpad);
  gather_kernel<<<Bv * Mv, 256, 0, stream>>>(xb, idx, g);
  gemm_bt<128,128,64,64><<<dim3(Vpad / 128, (Bv * Mv) / 128), 256, 0, stream>>>(
      g, we_t, be, lg, nullptr, Bv * Mv, Vv, Dv, 0);
  lsm_kernel<<<Bv * Mv, 256, 0, stream>>>(lg, out);
}